// Round 1
// baseline (3162.953 us; speedup 1.0000x reference)
//
#include <hip/hip_runtime.h>
#include <stdint.h>

typedef unsigned short ushort_t;
typedef float f32x4 __attribute__((ext_vector_type(4)));
typedef short short8 __attribute__((ext_vector_type(8)));

#define B_ 32
#define T_ 512
#define I_ 512
#define H_ 512
#define G_ 2048   // 4*H

// ---------- helpers ----------
__device__ __forceinline__ ushort_t f2bf(float f) {
    uint32_t u = __float_as_uint(f);
    u += 0x7FFFu + ((u >> 16) & 1u);   // RNE
    return (ushort_t)(u >> 16);
}
__device__ __forceinline__ float bf2f(ushort_t s) {
    return __uint_as_float(((uint32_t)s) << 16);
}
__device__ __forceinline__ float sigm(float x) { return 1.0f / (1.0f + __expf(-x)); }
__device__ __forceinline__ float tanhx(float x) {
    float e = __expf(-2.0f * fabsf(x));
    float t = (1.0f - e) / (1.0f + e);
    return x >= 0.0f ? t : -t;
}

// ---------- cast fp32 -> bf16 (vectorized) ----------
__global__ __launch_bounds__(256) void kcast(const float* __restrict__ in,
                                             ushort_t* __restrict__ out, int n4) {
    int i = blockIdx.x * 256 + threadIdx.x;
    if (i < n4) {
        float4 v = ((const float4*)in)[i];
        ushort4 o;
        o.x = f2bf(v.x); o.y = f2bf(v.y); o.z = f2bf(v.z); o.w = f2bf(v.w);
        ((ushort4*)out)[i] = o;
    }
}

// ---------- bias fold: bias = bx + bh ----------
__global__ __launch_bounds__(256) void kbias(const float* __restrict__ bx,
                                             const float* __restrict__ bh,
                                             float* __restrict__ bias) {
    int i = blockIdx.x * 256 + threadIdx.x;
    if (i < G_) bias[i] = bx[i] + bh[i];
}

// ---------- GEMM: gx[m][n] = sum_k xb[m][k]*wxb[n][k] + bias[n], bf16 out ----------
// 128x128 tile, BK=32, 256 threads (4 waves, 2x2 of 64x64), XOR-swizzled LDS.
__global__ __launch_bounds__(256, 2) void kgemm(const ushort_t* __restrict__ A,
                                                const ushort_t* __restrict__ Bm,
                                                const float* __restrict__ bias,
                                                ushort_t* __restrict__ C) {
    __shared__ __align__(16) ushort_t LA[4096];   // [128 rows][32 k] swizzled
    __shared__ __align__(16) ushort_t LB[4096];
    const int tid = threadIdx.x;
    const int lane = tid & 63, w = tid >> 6;
    const int quad = lane >> 4, l16 = lane & 15;
    const int bn = blockIdx.x, bm = blockIdx.y;
    const int wr = w >> 1, wc = w & 1;

    f32x4 acc[4][4] = {};

    for (int kt = 0; kt < 16; ++kt) {
#pragma unroll
        for (int r = 0; r < 2; ++r) {
            int o = r * 256 + tid;           // 16B unit index
            int m = o >> 2, slot = o & 3;
            int kc = slot ^ ((m >> 1) & 3);  // stored slot = kc ^ s(m)
            const ushort_t* ga = A  + (size_t)(bm * 128 + m) * I_ + kt * 32 + kc * 8;
            const ushort_t* gb = Bm + (size_t)(bn * 128 + m) * I_ + kt * 32 + kc * 8;
            __builtin_amdgcn_global_load_lds(
                (const __attribute__((address_space(1))) void*)ga,
                (__attribute__((address_space(3))) void*)(&LA[r * 2048 + w * 512]), 16, 0, 0);
            __builtin_amdgcn_global_load_lds(
                (const __attribute__((address_space(1))) void*)gb,
                (__attribute__((address_space(3))) void*)(&LB[r * 2048 + w * 512]), 16, 0, 0);
        }
        __syncthreads();

        short8 av[4], bv[4];
#pragma unroll
        for (int mt = 0; mt < 4; ++mt) {
            int mm = wr * 64 + mt * 16 + l16;
            av[mt] = *(const short8*)&LA[mm * 32 + ((quad ^ ((mm >> 1) & 3)) << 3)];
            int nn = wc * 64 + mt * 16 + l16;
            bv[mt] = *(const short8*)&LB[nn * 32 + ((quad ^ ((nn >> 1) & 3)) << 3)];
        }
#pragma unroll
        for (int mt = 0; mt < 4; ++mt)
#pragma unroll
            for (int nt = 0; nt < 4; ++nt)
                acc[mt][nt] = __builtin_amdgcn_mfma_f32_16x16x32_bf16(av[mt], bv[nt], acc[mt][nt], 0, 0, 0);
        __syncthreads();
    }

#pragma unroll
    for (int nt = 0; nt < 4; ++nt) {
        int n = bn * 128 + wc * 64 + nt * 16 + l16;
        float bvl = bias[n];
#pragma unroll
        for (int mt = 0; mt < 4; ++mt) {
#pragma unroll
            for (int rg = 0; rg < 4; ++rg) {
                int m = bm * 128 + wr * 64 + mt * 16 + quad * 4 + rg;
                C[(size_t)m * G_ + n] = f2bf(acc[mt][nt][rg] + bvl);
            }
        }
    }
}

// ---------- recurrence ----------
// 128 blocks = 4 groups x 32 blocks. Group g: batches g*8..g*8+7, rows 0-7 fwd, 8-15 bwd.
// Block j in group owns h-dims [j*16, j*16+16); wave w = gate section (i,f,g,o).
// Wh section held in registers (16 B-frags). h exchanged via global double buffer +
// monotonic per-group counter barrier with agent-scope fences.
__global__ __launch_bounds__(256, 2) void krec(const ushort_t* __restrict__ gx,
                                               const ushort_t* __restrict__ whb,
                                               ushort_t* __restrict__ hg,
                                               int* __restrict__ cnt,
                                               float* __restrict__ out) {
    __shared__ __align__(16) ushort_t hl[16 * 520];   // h tile, padded stride
    __shared__ float gates[4][16][16];                // [section][chain][dim]
    __shared__ float cl[256];                         // cell state
    const int tid = threadIdx.x;
    const int lane = tid & 63, w = tid >> 6;
    const int quad = lane >> 4, l16 = lane & 15;
    const int bk = blockIdx.x, grp = bk >> 5, j = bk & 31;
    const int PSTR = 4 * 16 * H_;                     // parity stride (ushorts)

    // load Wh B-frags for this wave's gate section, cols j*16..+16
    short8 bw[16];
    {
        const ushort_t* wp = whb + (size_t)(w * H_ + j * 16 + l16) * H_ + quad * 8;
#pragma unroll
        for (int kc = 0; kc < 16; ++kc) bw[kc] = *(const short8*)(wp + kc * 32);
    }
    cl[tid] = 0.0f;
    int* mycnt = cnt + grp * 32;
    ushort_t* hgrp = hg + (size_t)grp * 16 * H_;
    __syncthreads();

    for (int n = 0; n < 512; ++n) {
        // ---- wait for all 32 blocks of the group to finish step n-1 ----
        if (n > 0) {
            if (tid == 0) {
                while (__hip_atomic_load(mycnt, __ATOMIC_RELAXED, __HIP_MEMORY_SCOPE_AGENT) < 32 * n) {
                    __builtin_amdgcn_s_sleep(1);
                }
                __builtin_amdgcn_fence(__ATOMIC_ACQUIRE, "agent");
            }
            __syncthreads();
        }
        // ---- load h (16 x 512 bf16) into LDS ----
        const ushort_t* hsrc = hgrp + (size_t)(n & 1) * PSTR;
#pragma unroll
        for (int r = 0; r < 4; ++r) {
            int e = (r * 256 + tid) * 8;
            int row = e >> 9, col = e & 511;
            *(short8*)&hl[row * 520 + col] = *(const short8*)&hsrc[e];
        }
        __syncthreads();
        // ---- gates = h @ Wh_section^T ----
        f32x4 acc = {};
#pragma unroll
        for (int kc = 0; kc < 16; ++kc) {
            short8 av = *(const short8*)&hl[l16 * 520 + kc * 32 + quad * 8];
            acc = __builtin_amdgcn_mfma_f32_16x16x32_bf16(av, bw[kc], acc, 0, 0, 0);
        }
#pragma unroll
        for (int rg = 0; rg < 4; ++rg) gates[w][quad * 4 + rg][l16] = acc[rg];
        __syncthreads();
        // ---- cell update: thread -> (chain r, dim d) ----
        {
            int r = tid >> 4, d = tid & 15;
            int b = grp * 8 + (r & 7), dir = r >> 3;
            int te = dir ? (511 - n) : n;
            const ushort_t* gp = gx + (size_t)(b * T_ + te) * G_ + j * 16 + d;
            float gi = gates[0][r][d] + bf2f(gp[0]);
            float gf = gates[1][r][d] + bf2f(gp[512]);
            float gg = gates[2][r][d] + bf2f(gp[1024]);
            float go = gates[3][r][d] + bf2f(gp[1536]);
            float it = sigm(gi), ft = sigm(gf), gt = tanhx(gg), ot = sigm(go);
            float c = cl[tid] * ft + it * gt;
            cl[tid] = c;
            float h = ot * tanhx(c);
            out[(size_t)b * (T_ * 2 * H_) + (size_t)n * (2 * H_) + dir * H_ + j * 16 + d] = h;
            hgrp[(size_t)((n + 1) & 1) * PSTR + r * H_ + j * 16 + d] = f2bf(h);
        }
        // ---- arrive ----
        __syncthreads();
        if (tid == 0) {
            __builtin_amdgcn_fence(__ATOMIC_RELEASE, "agent");
            __hip_atomic_fetch_add(mycnt, 1, __ATOMIC_RELAXED, __HIP_MEMORY_SCOPE_AGENT);
        }
    }
}

// ---------- workspace layout (bytes) ----------
#define GX_OFF   ((size_t)0)                    // 16384*2048*2 = 67108864
#define XB_OFF   ((size_t)67108864)             // 16384*512*2 = 16777216
#define WXB_OFF  ((size_t)83886080)             // 2048*512*2  = 2097152
#define WHB_OFF  ((size_t)85983232)             // 2048*512*2  = 2097152
#define BIAS_OFF ((size_t)88080384)             // 2048*4      = 8192
#define HG_OFF   ((size_t)88088576)             // 2*4*16*512*2 = 131072
#define CNT_OFF  ((size_t)88219648)             // 4*32*4      = 512
#define WS_NEED  ((size_t)88220160)

extern "C" void kernel_launch(void* const* d_in, const int* in_sizes, int n_in,
                              void* d_out, int out_size, void* d_ws, size_t ws_size,
                              hipStream_t stream) {
    if (ws_size < WS_NEED) return;  // fail loudly via wrong output rather than corrupt

    const float* x  = (const float*)d_in[0];
    const float* Wx = (const float*)d_in[1];
    const float* bx = (const float*)d_in[2];
    const float* Wh = (const float*)d_in[3];
    const float* bh = (const float*)d_in[4];
    float* out = (float*)d_out;
    char* ws = (char*)d_ws;

    ushort_t* gx   = (ushort_t*)(ws + GX_OFF);
    ushort_t* xb   = (ushort_t*)(ws + XB_OFF);
    ushort_t* wxb  = (ushort_t*)(ws + WXB_OFF);
    ushort_t* whb  = (ushort_t*)(ws + WHB_OFF);
    float*    bias = (float*)(ws + BIAS_OFF);
    ushort_t* hg   = (ushort_t*)(ws + HG_OFF);
    int*      cnt  = (int*)(ws + CNT_OFF);

    // zero h double-buffer + barrier counters (ws is poisoned 0xAA each call)
    hipMemsetAsync(ws + HG_OFF, 0, (HG_OFF - HG_OFF) + 131072 + 512, stream);

    // casts
    kcast<<<dim3((B_ * T_ * I_ / 4 + 255) / 256), 256, 0, stream>>>(x, xb, B_ * T_ * I_ / 4);
    kcast<<<dim3((G_ * I_ / 4 + 255) / 256), 256, 0, stream>>>(Wx, wxb, G_ * I_ / 4);
    kcast<<<dim3((G_ * H_ / 4 + 255) / 256), 256, 0, stream>>>(Wh, whb, G_ * H_ / 4);
    kbias<<<dim3(G_ / 256), 256, 0, stream>>>(bx, bh, bias);

    // input projection GEMM: grid (N/128, M/128) = (16, 128)
    kgemm<<<dim3(G_ / 128, (B_ * T_) / 128), 256, 0, stream>>>(xb, wxb, bias, gx);

    // recurrence: 128 persistent blocks (4 groups x 32)
    krec<<<dim3(128), 256, 0, stream>>>(gx, whb, hg, cnt, out);
}

// Round 2
// 2176.791 us; speedup vs baseline: 1.4530x; 1.4530x over previous
//
#include <hip/hip_runtime.h>
#include <stdint.h>

typedef unsigned short ushort_t;
typedef float f32x4 __attribute__((ext_vector_type(4)));
typedef short short8 __attribute__((ext_vector_type(8)));

#define B_ 32
#define T_ 512
#define I_ 512
#define H_ 512
#define G_ 2048   // 4*H

// ---------- helpers ----------
__device__ __forceinline__ ushort_t f2bf(float f) {
    uint32_t u = __float_as_uint(f);
    u += 0x7FFFu + ((u >> 16) & 1u);   // RNE
    return (ushort_t)(u >> 16);
}
__device__ __forceinline__ float bf2f(ushort_t s) {
    return __uint_as_float(((uint32_t)s) << 16);
}
__device__ __forceinline__ float sigm(float x) { return 1.0f / (1.0f + __expf(-x)); }
__device__ __forceinline__ float tanhx(float x) {
    float e = __expf(-2.0f * fabsf(x));
    float t = (1.0f - e) / (1.0f + e);
    return x >= 0.0f ? t : -t;
}

// ---------- cast fp32 -> bf16 (vectorized) ----------
__global__ __launch_bounds__(256) void kcast(const float* __restrict__ in,
                                             ushort_t* __restrict__ out, int n4) {
    int i = blockIdx.x * 256 + threadIdx.x;
    if (i < n4) {
        float4 v = ((const float4*)in)[i];
        ushort4 o;
        o.x = f2bf(v.x); o.y = f2bf(v.y); o.z = f2bf(v.z); o.w = f2bf(v.w);
        ((ushort4*)out)[i] = o;
    }
}

// ---------- bias fold: bias = bx + bh ----------
__global__ __launch_bounds__(256) void kbias(const float* __restrict__ bx,
                                             const float* __restrict__ bh,
                                             float* __restrict__ bias) {
    int i = blockIdx.x * 256 + threadIdx.x;
    if (i < G_) bias[i] = bx[i] + bh[i];
}

// ---------- GEMM: gx[m][n'] = sum_k xb[m][k]*wxb[n][k] + bias[n], bf16 out ----------
// Column layout swizzled for krec: logical n = gate*512 + jj*16 + d  ->  n' = jj*64 + gate*16 + d
// so each recurrence block's per-(b,t) slice is 64 contiguous values.
__global__ __launch_bounds__(256, 2) void kgemm(const ushort_t* __restrict__ A,
                                                const ushort_t* __restrict__ Bm,
                                                const float* __restrict__ bias,
                                                ushort_t* __restrict__ C) {
    __shared__ __align__(16) ushort_t LA[4096];   // [128 rows][32 k] swizzled
    __shared__ __align__(16) ushort_t LB[4096];
    const int tid = threadIdx.x;
    const int lane = tid & 63, w = tid >> 6;
    const int quad = lane >> 4, l16 = lane & 15;
    const int bn = blockIdx.x, bm = blockIdx.y;
    const int wr = w >> 1, wc = w & 1;

    f32x4 acc[4][4] = {};

    for (int kt = 0; kt < 16; ++kt) {
#pragma unroll
        for (int r = 0; r < 2; ++r) {
            int o = r * 256 + tid;           // 16B unit index
            int m = o >> 2, slot = o & 3;
            int kc = slot ^ ((m >> 1) & 3);  // stored slot = kc ^ s(m)
            const ushort_t* ga = A  + (size_t)(bm * 128 + m) * I_ + kt * 32 + kc * 8;
            const ushort_t* gb = Bm + (size_t)(bn * 128 + m) * I_ + kt * 32 + kc * 8;
            __builtin_amdgcn_global_load_lds(
                (const __attribute__((address_space(1))) void*)ga,
                (__attribute__((address_space(3))) void*)(&LA[r * 2048 + w * 512]), 16, 0, 0);
            __builtin_amdgcn_global_load_lds(
                (const __attribute__((address_space(1))) void*)gb,
                (__attribute__((address_space(3))) void*)(&LB[r * 2048 + w * 512]), 16, 0, 0);
        }
        __syncthreads();

        short8 av[4], bv[4];
#pragma unroll
        for (int mt = 0; mt < 4; ++mt) {
            int mm = wr * 64 + mt * 16 + l16;
            av[mt] = *(const short8*)&LA[mm * 32 + ((quad ^ ((mm >> 1) & 3)) << 3)];
            int nn = wc * 64 + mt * 16 + l16;
            bv[mt] = *(const short8*)&LB[nn * 32 + ((quad ^ ((nn >> 1) & 3)) << 3)];
        }
#pragma unroll
        for (int mt = 0; mt < 4; ++mt)
#pragma unroll
            for (int nt = 0; nt < 4; ++nt)
                acc[mt][nt] = __builtin_amdgcn_mfma_f32_16x16x32_bf16(av[mt], bv[nt], acc[mt][nt], 0, 0, 0);
        __syncthreads();
    }

#pragma unroll
    for (int nt = 0; nt < 4; ++nt) {
        int n = bn * 128 + wc * 64 + nt * 16 + l16;      // logical gate-space column
        int gate = n >> 9, jj = (n >> 4) & 31, d = n & 15;
        int np = jj * 64 + gate * 16 + d;                // swizzled storage column
        float bvl = bias[n];
#pragma unroll
        for (int mt = 0; mt < 4; ++mt) {
#pragma unroll
            for (int rg = 0; rg < 4; ++rg) {
                int m = bm * 128 + wr * 64 + mt * 16 + quad * 4 + rg;
                C[(size_t)m * G_ + np] = f2bf(acc[mt][nt][rg] + bvl);
            }
        }
    }
}

// ---------- recurrence ----------
// 128 blocks = 4 groups x 32 blocks. Group g: batches g*8..g*8+7, chains 0-7 fwd, 8-15 bwd.
// Block j owns h-dims [j*16, j*16+16); wave w = gate section (i,f,g,o), Wh section in VGPRs.
// Cross-block exchange: per-access AGENT-scope atomics (sc1, no bulk cache fences) +
// per-block flag array. h double-buffered in global by step parity.
__global__ __launch_bounds__(256, 2) void krec(const ushort_t* __restrict__ gx,
                                               const ushort_t* __restrict__ whb,
                                               unsigned long long* __restrict__ hg,
                                               int* __restrict__ flags,
                                               float* __restrict__ out) {
    __shared__ __align__(16) ushort_t hl[16 * 520];   // h tile, padded stride
    __shared__ float gates[4][16][16];                // [gate][chain][dim]
    const int tid = threadIdx.x;
    const int lane = tid & 63, w = tid >> 6;
    const int quad = lane >> 4, l16 = lane & 15;
    const int bk = blockIdx.x, grp = bk >> 5, j = bk & 31;

    // Wh B-frags for this wave's gate section, cols j*16..+16 (rows of Wh = gate outputs)
    short8 bw[16];
    {
        const ushort_t* wp = whb + (size_t)(w * H_ + j * 16 + l16) * H_ + quad * 8;
#pragma unroll
        for (int kc = 0; kc < 16; ++kc) bw[kc] = *(const short8*)(wp + kc * 32);
    }

    const int r = tid >> 4, d = tid & 15;     // chain, dim for cell update
    const int b = grp * 8 + (r & 7), dir = r >> 3;
    float c = 0.0f;                           // cell state in register

    int* fl = flags + grp * 64;
    unsigned long long* hgrp = hg + (size_t)grp * 4096;   // 2 parities x 2048 units

    for (int n = 0; n < 512; ++n) {
        // ---- prefetch gx for this step (independent of h) ----
        int te = dir ? (511 - n) : n;
        const ushort_t* gp = gx + (size_t)(b * T_ + te) * G_ + j * 64 + d;
        ushort_t g0 = gp[0], g1 = gp[16], g2 = gp[32], g3 = gp[48];

        // ---- wait for all 32 blocks of the group to have completed step n-1 ----
        if (n > 0) {
            const int* fp = fl + (lane & 31);
            for (;;) {
                int f = __hip_atomic_load(fp, __ATOMIC_RELAXED, __HIP_MEMORY_SCOPE_AGENT);
                if (__all(f >= n)) break;
            }
        }

        // ---- coherent load h (16 x 512 bf16 = 2048 x 8B) -> LDS ----
        const unsigned long long* hsrc = hgrp + (size_t)(n & 1) * 2048;
#pragma unroll
        for (int k = 0; k < 8; ++k) {
            int u = k * 256 + tid;
            unsigned long long v = __hip_atomic_load(hsrc + u, __ATOMIC_RELAXED, __HIP_MEMORY_SCOPE_AGENT);
            int row = u >> 7, col = (u & 127) * 4;
            *(unsigned long long*)&hl[row * 520 + col] = v;
        }
        __syncthreads();

        // ---- gates = h @ Wh_section^T (two independent MFMA chains) ----
        f32x4 acc0 = {}, acc1 = {};
#pragma unroll
        for (int kc = 0; kc < 16; kc += 2) {
            short8 av0 = *(const short8*)&hl[l16 * 520 + kc * 32 + quad * 8];
            acc0 = __builtin_amdgcn_mfma_f32_16x16x32_bf16(av0, bw[kc], acc0, 0, 0, 0);
            short8 av1 = *(const short8*)&hl[l16 * 520 + (kc + 1) * 32 + quad * 8];
            acc1 = __builtin_amdgcn_mfma_f32_16x16x32_bf16(av1, bw[kc + 1], acc1, 0, 0, 0);
        }
        f32x4 acc = acc0 + acc1;
#pragma unroll
        for (int rg = 0; rg < 4; ++rg) gates[w][quad * 4 + rg][l16] = acc[rg];
        __syncthreads();

        // ---- cell update: thread -> (chain r, dim d) ----
        float gi = gates[0][r][d] + bf2f(g0);
        float gf = gates[1][r][d] + bf2f(g1);
        float gg = gates[2][r][d] + bf2f(g2);
        float go = gates[3][r][d] + bf2f(g3);
        float it = sigm(gi), ft = sigm(gf), gt = tanhx(gg), ot = sigm(go);
        c = c * ft + it * gt;
        float h = ot * tanhx(c);
        out[(size_t)b * (T_ * 2 * H_) + (size_t)n * (2 * H_) + dir * H_ + j * 16 + d] = h;

        // ---- pack 4 bf16 per 8B unit via shuffles, coherent-store to parity (n+1)&1 ----
        int hv = (int)f2bf(h);
        int base = lane & ~3;
        int v1 = __shfl(hv, base + 1);
        int v2 = __shfl(hv, base + 2);
        int v3 = __shfl(hv, base + 3);
        if ((lane & 3) == 0) {
            unsigned long long packed = (unsigned long long)(unsigned)hv
                                      | ((unsigned long long)(unsigned)v1 << 16)
                                      | ((unsigned long long)(unsigned)v2 << 32)
                                      | ((unsigned long long)(unsigned)v3 << 48);
            int u = r * 128 + j * 4 + (d >> 2);
            __hip_atomic_store(hgrp + (size_t)((n + 1) & 1) * 2048 + u, packed,
                               __ATOMIC_RELAXED, __HIP_MEMORY_SCOPE_AGENT);
        }

        // ---- drain store acks, then arrive ----
        __builtin_amdgcn_s_waitcnt(0);
        __syncthreads();
        if (tid == 0) {
            __hip_atomic_store(fl + j, n + 1, __ATOMIC_RELAXED, __HIP_MEMORY_SCOPE_AGENT);
        }
    }
}

// ---------- workspace layout (bytes) ----------
#define GX_OFF    ((size_t)0)                    // 16384*2048*2 = 67108864
#define XB_OFF    ((size_t)67108864)             // 16384*512*2 = 16777216
#define WXB_OFF   ((size_t)83886080)             // 2048*512*2  = 2097152
#define WHB_OFF   ((size_t)85983232)             // 2048*512*2  = 2097152
#define BIAS_OFF  ((size_t)88080384)             // 2048*4      = 8192
#define HG_OFF    ((size_t)88088576)             // 4 grp * 2 par * 16KB = 131072
#define FLAG_OFF  ((size_t)88219648)             // 4*64*4      = 1024
#define WS_NEED   ((size_t)88220672)

extern "C" void kernel_launch(void* const* d_in, const int* in_sizes, int n_in,
                              void* d_out, int out_size, void* d_ws, size_t ws_size,
                              hipStream_t stream) {
    if (ws_size < WS_NEED) return;

    const float* x  = (const float*)d_in[0];
    const float* Wx = (const float*)d_in[1];
    const float* bx = (const float*)d_in[2];
    const float* Wh = (const float*)d_in[3];
    const float* bh = (const float*)d_in[4];
    float* out = (float*)d_out;
    char* ws = (char*)d_ws;

    ushort_t* gx   = (ushort_t*)(ws + GX_OFF);
    ushort_t* xb   = (ushort_t*)(ws + XB_OFF);
    ushort_t* wxb  = (ushort_t*)(ws + WXB_OFF);
    ushort_t* whb  = (ushort_t*)(ws + WHB_OFF);
    float*    bias = (float*)(ws + BIAS_OFF);
    unsigned long long* hg = (unsigned long long*)(ws + HG_OFF);
    int*      flags = (int*)(ws + FLAG_OFF);

    // zero h double-buffer + flags (ws is poisoned 0xAA before every call)
    hipMemsetAsync(ws + HG_OFF, 0, 131072 + 1024, stream);

    // casts
    kcast<<<dim3((B_ * T_ * I_ / 4 + 255) / 256), 256, 0, stream>>>(x, xb, B_ * T_ * I_ / 4);
    kcast<<<dim3((G_ * I_ / 4 + 255) / 256), 256, 0, stream>>>(Wx, wxb, G_ * I_ / 4);
    kcast<<<dim3((G_ * H_ / 4 + 255) / 256), 256, 0, stream>>>(Wh, whb, G_ * H_ / 4);
    kbias<<<dim3(G_ / 256), 256, 0, stream>>>(bx, bh, bias);

    // input projection GEMM: grid (N/128, M/128) = (16, 128)
    kgemm<<<dim3(G_ / 128, (B_ * T_) / 128), 256, 0, stream>>>(xb, wxb, bias, gx);

    // recurrence: 128 persistent blocks (4 groups x 32)
    krec<<<dim3(128), 256, 0, stream>>>(gx, whb, hg, flags, out);
}